// Round 6
// baseline (80.451 us; speedup 1.0000x reference)
//
#include <hip/hip_runtime.h>
#include <math.h>

// LML layer: per row solve sum_j sigmoid(x_j + nu) = N (N=5), output sigmoid(x+nu).
// One wave (64 lanes) per row; 16 elements/lane in registers as E_j = exp(+x_j).
//
// u = exp(-nu):  sigmoid(x_j+nu) = E_j/(E_j+u).
//   g(u) = sum E/(E+u) - N is convex, strictly decreasing for u>0 (any data).
//   u0 = (sum E)/N  =>  g(u0) < 0; convexity => plain Newton globally
//   convergent (one left overshoot, then monotone from the left).
// Pass structure (3 passes over E):
//   pass 1: load x, E=exp2(x*log2e), s0 = sum E   (no rcp needed)
//   pass 2: Newton iter A at u0 -> u1
//   pass 3: Newton iter B at u1: store only r=rcp(E+u1); after reduction gives
//           step delta, emit y = (E*r)*(1 - r*delta)  (1st-order Taylor,
//           2nd-order err ~1e-7). Storing r instead of {t,tr} keeps peak live
//           floats at 32 (E+r) -> VGPR well under the 64-reg / 8-wave-per-SIMD
//           occupancy cliff, so all 8192 waves (32/CU) stay co-resident.
// Butterfly wave-reductions -> sums bitwise identical across lanes -> all
// control flow wave-uniform. No LDS, no barriers. NT stores (streaming out).

constexpr int COLS = 1024;
constexpr int NTOP = 5;
constexpr int VPL  = COLS / 64;   // 16 values per lane
constexpr int WPB  = 4;           // waves (rows) per block

typedef float vfloat4 __attribute__((ext_vector_type(4)));

__device__ __forceinline__ float wave_sum(float v) {
#pragma unroll
    for (int m = 32; m >= 1; m >>= 1) v += __shfl_xor(v, m, 64);
    return v;
}
// Two interleaved reductions so the shfl latencies pipeline.
__device__ __forceinline__ void wave_sum2(float& a, float& b) {
#pragma unroll
    for (int m = 32; m >= 1; m >>= 1) {
        float ta = __shfl_xor(a, m, 64);
        float tb = __shfl_xor(b, m, 64);
        a += ta; b += tb;
    }
}

__global__ __launch_bounds__(WPB * 64) void lml_kernel(
        const float* __restrict__ x, float* __restrict__ y, int rows) {
    const int wave = threadIdx.x >> 6;
    const int lane = threadIdx.x & 63;
    const int row  = blockIdx.x * WPB + wave;
    if (row >= rows) return;

    const float* xr = x + (size_t)row * COLS;
    float*       yr = y + (size_t)row * COLS;

    constexpr float L2E = 1.4426950408889634f;   // log2(e)

    // ---- pass 1: load + exp, row-sum of E ----
    float E[VPL];
    float s0 = 0.0f;
#pragma unroll
    for (int w = 0; w < VPL / 4; ++w) {
        vfloat4 v = *reinterpret_cast<const vfloat4*>(xr + w * 256 + lane * 4);
        float e0 = __builtin_amdgcn_exp2f(v.x * L2E);
        float e1 = __builtin_amdgcn_exp2f(v.y * L2E);
        float e2 = __builtin_amdgcn_exp2f(v.z * L2E);
        float e3 = __builtin_amdgcn_exp2f(v.w * L2E);
        E[w * 4 + 0] = e0; E[w * 4 + 1] = e1;
        E[w * 4 + 2] = e2; E[w * 4 + 3] = e3;
        s0 += (e0 + e1) + (e2 + e3);
    }
    s0 = wave_sum(s0);                     // identical on all lanes

    float u = s0 * (1.0f / (float)NTOP);   // u0: g(u0) < 0 guaranteed

    // ---- pass 2: Newton iteration A ----
    {
        float G = 0.0f, H = 0.0f;
#pragma unroll
        for (int j = 0; j < VPL; ++j) {
            float r = __builtin_amdgcn_rcpf(E[j] + u);
            float t = E[j] * r;            // sigmoid value
            G += t;
            H = fmaf(t, r, H);             // -g'(u) = sum E/(E+u)^2
        }
        wave_sum2(G, H);
        u = fmaf(G - (float)NTOP, __builtin_amdgcn_rcpf(H), u);
        u = fmaxf(u, 1e-30f);              // paranoia, never hit for sane data
    }

    // ---- pass 3: Newton iteration B fused with epilogue (Taylor) ----
    float R[VPL];                          // only r is stored: 32 live floats
    float G = 0.0f, H = 0.0f;
#pragma unroll
    for (int j = 0; j < VPL; ++j) {
        float r = __builtin_amdgcn_rcpf(E[j] + u);
        R[j] = r;
        float t = E[j] * r;
        G += t;
        H = fmaf(t, r, H);                 // sum E/(E+u)^2
    }
    wave_sum2(G, H);
    const float delta = (G - (float)NTOP) * __builtin_amdgcn_rcpf(H); // u step

#pragma unroll
    for (int w = 0; w < VPL / 4; ++w) {
        vfloat4 o;
        // y = t*(1 - r*delta) = E/(E+u1) - E/(E+u1)^2 * delta
        o.x = (E[w*4+0] * R[w*4+0]) * fmaf(-delta, R[w*4+0], 1.0f);
        o.y = (E[w*4+1] * R[w*4+1]) * fmaf(-delta, R[w*4+1], 1.0f);
        o.z = (E[w*4+2] * R[w*4+2]) * fmaf(-delta, R[w*4+2], 1.0f);
        o.w = (E[w*4+3] * R[w*4+3]) * fmaf(-delta, R[w*4+3], 1.0f);
        __builtin_nontemporal_store(o, reinterpret_cast<vfloat4*>(yr + w * 256 + lane * 4));
    }
}

extern "C" void kernel_launch(void* const* d_in, const int* in_sizes, int n_in,
                              void* d_out, int out_size, void* d_ws, size_t ws_size,
                              hipStream_t stream) {
    const float* x = (const float*)d_in[0];
    float* y = (float*)d_out;
    const int rows = in_sizes[0] / COLS;   // 8192
    const int grid = (rows + WPB - 1) / WPB;
    lml_kernel<<<grid, WPB * 64, 0, stream>>>(x, y, rows);
}

// Round 7
// 80.330 us; speedup vs baseline: 1.0015x; 1.0015x over previous
//
#include <hip/hip_runtime.h>
#include <math.h>

// LML layer: per row solve sum_j sigmoid(x_j + nu) = N (N=5), output sigmoid(x+nu).
// u = exp(-nu):  sigmoid(x_j+nu) = E_j/(E_j+u),  E_j = exp(x_j).
//   g(u) = sum E/(E+u) - N is convex, strictly decreasing for u>0 (any data).
//   u0 = (sum E)/N  =>  g(u0) < 0; convexity => plain Newton globally
//   convergent. 2 Newton evals needed (worst-tail rows: 1 eval leaves ~3e-3).
//
// TWO ROWS PER WAVE, lockstep: halves the grid (4096 waves = 16/CU, one
// co-resident shot at 4 waves/SIMD), compresses all global reads to the kernel
// front (8 loads in flight before any compute), and shares every butterfly
// reduction between the two rows (wave_sum4: 4 interleaved accumulators) --
// halving reduction-chain latency and shfl count per row. This attacks the
// phase-serialization (load -> solve -> store in lockstep across a single
// wave generation) that held R5/R6 at ~16.6 us vs the ~11 us mem floor.
//
// Pass structure per row pair (2 f-evals/row):
//   pass 1: E=exp2(x*log2e), s0 = sum E          -> u0 = s0/N
//   pass 2: Newton at u0 -> u1
//   pass 3: Newton at u1, keep r=rcp(E+u1); step delta ->
//           y = (E*r)*(1 - r*delta)   (1st-order Taylor, err ~2e-5)
// All reductions butterfly -> bitwise identical across lanes -> wave-uniform
// control flow. No LDS, no barriers. NT vector stores.

constexpr int COLS = 1024;
constexpr int NTOP = 5;
constexpr int VPL  = COLS / 64;   // 16 values per lane
constexpr int WPB  = 4;           // waves per block (each wave: 2 rows)

typedef float vfloat4 __attribute__((ext_vector_type(4)));

__device__ __forceinline__ void wave_sum2(float& a, float& b) {
#pragma unroll
    for (int m = 32; m >= 1; m >>= 1) {
        float ta = __shfl_xor(a, m, 64);
        float tb = __shfl_xor(b, m, 64);
        a += ta; b += tb;
    }
}
__device__ __forceinline__ void wave_sum4(float& a, float& b, float& c, float& d) {
#pragma unroll
    for (int m = 32; m >= 1; m >>= 1) {
        float ta = __shfl_xor(a, m, 64);
        float tb = __shfl_xor(b, m, 64);
        float tc = __shfl_xor(c, m, 64);
        float td = __shfl_xor(d, m, 64);
        a += ta; b += tb; c += tc; d += td;
    }
}

__global__ __launch_bounds__(WPB * 64, 4) void lml_kernel(
        const float* __restrict__ x, float* __restrict__ y, int rows) {
    const int wave = threadIdx.x >> 6;
    const int lane = threadIdx.x & 63;
    const int pair = blockIdx.x * WPB + wave;
    const int rowA = pair * 2;
    if (rowA >= rows) return;
    const int rowB = (rowA + 1 < rows) ? rowA + 1 : rowA;  // rows is even; safety

    const float* xa = x + (size_t)rowA * COLS;
    const float* xb = x + (size_t)rowB * COLS;
    float*       ya = y + (size_t)rowA * COLS;
    float*       yb = y + (size_t)rowB * COLS;

    constexpr float L2E = 1.4426950408889634f;   // log2(e)

    // ---- issue ALL global reads up front (8 dwordx4 in flight) ----
    vfloat4 va[VPL / 4], vb[VPL / 4];
#pragma unroll
    for (int w = 0; w < VPL / 4; ++w)
        va[w] = *reinterpret_cast<const vfloat4*>(xa + w * 256 + lane * 4);
#pragma unroll
    for (int w = 0; w < VPL / 4; ++w)
        vb[w] = *reinterpret_cast<const vfloat4*>(xb + w * 256 + lane * 4);

    // ---- pass 1: exp + row sums ----
    float EA[VPL], EB[VPL];
    float sA = 0.0f, sB = 0.0f;
#pragma unroll
    for (int w = 0; w < VPL / 4; ++w) {
        float a0 = __builtin_amdgcn_exp2f(va[w].x * L2E);
        float a1 = __builtin_amdgcn_exp2f(va[w].y * L2E);
        float a2 = __builtin_amdgcn_exp2f(va[w].z * L2E);
        float a3 = __builtin_amdgcn_exp2f(va[w].w * L2E);
        EA[w*4+0]=a0; EA[w*4+1]=a1; EA[w*4+2]=a2; EA[w*4+3]=a3;
        sA += (a0 + a1) + (a2 + a3);
        float b0 = __builtin_amdgcn_exp2f(vb[w].x * L2E);
        float b1 = __builtin_amdgcn_exp2f(vb[w].y * L2E);
        float b2 = __builtin_amdgcn_exp2f(vb[w].z * L2E);
        float b3 = __builtin_amdgcn_exp2f(vb[w].w * L2E);
        EB[w*4+0]=b0; EB[w*4+1]=b1; EB[w*4+2]=b2; EB[w*4+3]=b3;
        sB += (b0 + b1) + (b2 + b3);
    }
    wave_sum2(sA, sB);                       // identical on all lanes

    float uA = sA * (1.0f / (float)NTOP);    // g(u0) < 0 guaranteed
    float uB = sB * (1.0f / (float)NTOP);

    // ---- pass 2: Newton iteration A (both rows) ----
    {
        float GA = 0.0f, HA = 0.0f, GB = 0.0f, HB = 0.0f;
#pragma unroll
        for (int j = 0; j < VPL; ++j) {
            float ra = __builtin_amdgcn_rcpf(EA[j] + uA);
            float ta = EA[j] * ra;
            GA += ta; HA = fmaf(ta, ra, HA);
            float rb = __builtin_amdgcn_rcpf(EB[j] + uB);
            float tb = EB[j] * rb;
            GB += tb; HB = fmaf(tb, rb, HB);
        }
        wave_sum4(GA, HA, GB, HB);
        uA = fmaf(GA - (float)NTOP, __builtin_amdgcn_rcpf(HA), uA);
        uB = fmaf(GB - (float)NTOP, __builtin_amdgcn_rcpf(HB), uB);
        uA = fmaxf(uA, 1e-30f);
        uB = fmaxf(uB, 1e-30f);
    }

    // ---- pass 3: Newton iteration B fused with epilogue (Taylor) ----
    float RA[VPL], RB[VPL];
    float GA = 0.0f, HA = 0.0f, GB = 0.0f, HB = 0.0f;
#pragma unroll
    for (int j = 0; j < VPL; ++j) {
        float ra = __builtin_amdgcn_rcpf(EA[j] + uA);
        RA[j] = ra;
        float ta = EA[j] * ra;
        GA += ta; HA = fmaf(ta, ra, HA);
        float rb = __builtin_amdgcn_rcpf(EB[j] + uB);
        RB[j] = rb;
        float tb = EB[j] * rb;
        GB += tb; HB = fmaf(tb, rb, HB);
    }
    wave_sum4(GA, HA, GB, HB);
    const float dA = (GA - (float)NTOP) * __builtin_amdgcn_rcpf(HA);
    const float dB = (GB - (float)NTOP) * __builtin_amdgcn_rcpf(HB);

#pragma unroll
    for (int w = 0; w < VPL / 4; ++w) {
        vfloat4 o;
        o.x = (EA[w*4+0] * RA[w*4+0]) * fmaf(-dA, RA[w*4+0], 1.0f);
        o.y = (EA[w*4+1] * RA[w*4+1]) * fmaf(-dA, RA[w*4+1], 1.0f);
        o.z = (EA[w*4+2] * RA[w*4+2]) * fmaf(-dA, RA[w*4+2], 1.0f);
        o.w = (EA[w*4+3] * RA[w*4+3]) * fmaf(-dA, RA[w*4+3], 1.0f);
        __builtin_nontemporal_store(o, reinterpret_cast<vfloat4*>(ya + w * 256 + lane * 4));
    }
#pragma unroll
    for (int w = 0; w < VPL / 4; ++w) {
        vfloat4 o;
        o.x = (EB[w*4+0] * RB[w*4+0]) * fmaf(-dB, RB[w*4+0], 1.0f);
        o.y = (EB[w*4+1] * RB[w*4+1]) * fmaf(-dB, RB[w*4+1], 1.0f);
        o.z = (EB[w*4+2] * RB[w*4+2]) * fmaf(-dB, RB[w*4+2], 1.0f);
        o.w = (EB[w*4+3] * RB[w*4+3]) * fmaf(-dB, RB[w*4+3], 1.0f);
        __builtin_nontemporal_store(o, reinterpret_cast<vfloat4*>(yb + w * 256 + lane * 4));
    }
}

extern "C" void kernel_launch(void* const* d_in, const int* in_sizes, int n_in,
                              void* d_out, int out_size, void* d_ws, size_t ws_size,
                              hipStream_t stream) {
    const float* x = (const float*)d_in[0];
    float* y = (float*)d_out;
    const int rows = in_sizes[0] / COLS;           // 8192
    const int pairs = (rows + 1) / 2;              // 4096 waves
    const int grid = (pairs + WPB - 1) / WPB;      // 1024 blocks
    lml_kernel<<<grid, WPB * 64, 0, stream>>>(x, y, rows);
}